// Round 3
// baseline (1221.158 us; speedup 1.0000x reference)
//
#include <hip/hip_runtime.h>
#include <stdint.h>

// Problem constants
#define BB   4
#define NS   10000
#define NT   10000
#define EE   160000
#define KK   16
#define DD   128

typedef short s8v  __attribute__((ext_vector_type(8)));   // 8 bf16 (4 VGPRs)
typedef float f4v  __attribute__((ext_vector_type(4)));   // 4 fp32 acc
typedef unsigned int u4v __attribute__((ext_vector_type(4)));  // 16B copy unit

static __device__ __forceinline__ float bf2f(unsigned short u) {
    union { unsigned int i; float f; } v; v.i = ((unsigned int)u) << 16; return v.f;
}
static __device__ __forceinline__ unsigned short f2bf(float f) {
    union { float f; unsigned int i; } v; v.f = f;
    unsigned int x = v.i;
    unsigned int r = x + 0x7fffu + ((x >> 16) & 1u);   // round-to-nearest-even
    return (unsigned short)(r >> 16);
}

// A-fragment (fp32 source, contiguous 8 floats) via two dwordx4 loads
static __device__ __forceinline__ s8v load_afrag_f32(const float* __restrict__ p) {
    const float4 v0 = *(const float4*)(p);
    const float4 v1 = *(const float4*)(p + 4);
    s8v r;
    r[0] = (short)f2bf(v0.x); r[1] = (short)f2bf(v0.y);
    r[2] = (short)f2bf(v0.z); r[3] = (short)f2bf(v0.w);
    r[4] = (short)f2bf(v1.x); r[5] = (short)f2bf(v1.y);
    r[6] = (short)f2bf(v1.z); r[7] = (short)f2bf(v1.w);
    return r;
}

// ---------------------------------------------------------------------------
// Fragment-major bf16 weight staging.
// For matrix m, fragment (c,t), lane: 8 contiguous bf16 = W[32c+8q+j][16t+np]
// One dwordx4 load per B-fragment at use time (L2-resident, 32 KB/matrix).
// ---------------------------------------------------------------------------
#define WFRAG_U16 (32 * 64 * 8)   // per matrix: 16384 u16 = 32 KB

__global__ void wprep_kernel(const float* __restrict__ W0, const float* __restrict__ W1,
                             const float* __restrict__ W2, const float* __restrict__ W3,
                             const float* __restrict__ W4, unsigned short* __restrict__ out)
{
    const float* W;
    switch (blockIdx.x) {
        case 0: W = W0; break;
        case 1: W = W1; break;
        case 2: W = W2; break;
        case 3: W = W3; break;
        default: W = W4; break;
    }
    unsigned short* O = out + (size_t)blockIdx.x * WFRAG_U16;
    const int lane = threadIdx.x & 63;
    const int wave = threadIdx.x >> 6;
    const int np = lane & 15, q = lane >> 4;
    for (int ct = wave; ct < 32; ct += 4) {
        const int c = ct >> 3, t = ct & 7;
        const float* p = W + (32 * c + 8 * q) * DD + 16 * t + np;
        s8v v;
#pragma unroll
        for (int j = 0; j < 8; ++j) v[j] = (short)f2bf(p[j * DD]);
        *(s8v*)(O + ((size_t)ct * 64 + lane) * 8) = v;
    }
}

// ---------------------------------------------------------------------------
// K1: s_proj = src @ W_s2e ; t_proj = tgt @ W_t2e  (bf16, PERMUTED row layout)
// Permuted layout: value for col (16t+np) stored at row*128 + np*8 + t.
// Writer lane stores 8 contiguous bf16 (one 16B store per output row chunk);
// gather reader later loads its 8 needed values as one 16B load.
// ---------------------------------------------------------------------------
__global__ __launch_bounds__(256, 4)
void proj_kernel(const float* __restrict__ src,
                 const float* __restrict__ tgt,
                 const s8v* __restrict__ wfS,
                 const s8v* __restrict__ wfT,
                 unsigned short* __restrict__ out_s,
                 unsigned short* __restrict__ out_t)
{
    const int lane = threadIdx.x & 63;
    const int wave = threadIdx.x >> 6;
    const int np = lane & 15, q = lane >> 4;

    const float* X; const s8v* wf; unsigned short* O;
    if (blockIdx.y == 0) { X = src; wf = wfS; O = out_s; }
    else                 { X = tgt; wf = wfT; O = out_t; }

    const int NTILES = (BB * NS) / 16;      // 2500
    const int nw = gridDim.x * 4;
    for (int tile = blockIdx.x * 4 + wave; tile < NTILES; tile += nw) {
        const float* abase = X + (size_t)(tile * 16 + np) * DD + 8 * q;
        s8v a[4];
#pragma unroll
        for (int c = 0; c < 4; ++c) a[c] = load_afrag_f32(abase + 32 * c);
        f4v acc[8];
        const f4v zero = {0.f, 0.f, 0.f, 0.f};
#pragma unroll
        for (int t = 0; t < 8; ++t) acc[t] = zero;
#pragma unroll
        for (int c = 0; c < 4; ++c)
#pragma unroll
            for (int t = 0; t < 8; ++t)
                acc[t] = __builtin_amdgcn_mfma_f32_16x16x32_bf16(a[c], wf[(c * 8 + t) * 64 + lane], acc[t], 0, 0, 0);
        // C layout: row = 4q+r, col = 16t+np  ->  permuted store np*8+t
#pragma unroll
        for (int r = 0; r < 4; ++r) {
            s8v v;
#pragma unroll
            for (int t = 0; t < 8; ++t) v[t] = (short)f2bf(acc[t][r]);
            *(s8v*)(O + (size_t)(tile * 16 + 4 * q + r) * DD + np * 8) = v;
        }
    }
}

// ---------------------------------------------------------------------------
// K2: out0 = bond + LN(silu(bond@W_e2e + s_proj[src_order] + t_proj[tgt_order]))
//     optionally writes d_bond (bf16, NORMAL layout) to ws
// ---------------------------------------------------------------------------
__global__ __launch_bounds__(256, 4)
void bond_kernel(const float* __restrict__ bond,
                 const s8v* __restrict__ wfE,
                 const unsigned short* __restrict__ sproj,
                 const unsigned short* __restrict__ tproj,
                 const int* __restrict__ src_order,
                 const int* __restrict__ tgt_order,
                 const float* __restrict__ g1,
                 const float* __restrict__ b1,
                 float* __restrict__ out0,
                 unsigned short* __restrict__ dbond)
{
    const int lane = threadIdx.x & 63;
    const int wave = threadIdx.x >> 6;
    const int np = lane & 15, q = lane >> 4;
    const int b = blockIdx.y;

    float gv[8], bv[8];
#pragma unroll
    for (int t = 0; t < 8; ++t) { gv[t] = g1[16 * t + np]; bv[t] = b1[16 * t + np]; }

    const int TPB = EE / 16;                 // 10000 tiles per batch
    const int nw = gridDim.x * 4;
    for (int tile = blockIdx.x * 4 + wave; tile < TPB; tile += nw) {
        const int e0 = tile * 16;
        const size_t rowbase = ((size_t)b * EE + e0) * DD;

        // A fragments (bond rows)
        const float* abase = bond + rowbase + (size_t)np * DD + 8 * q;
        s8v a[4];
#pragma unroll
        for (int c = 0; c < 4; ++c) a[c] = load_afrag_f32(abase + 32 * c);

        // edge indices (one int4 each) + gathers issued BEFORE the MFMAs so the
        // MFMA chain + weight loads hide the dependent-gather latency
        const int4 se4 = *(const int4*)(src_order + e0 + 4 * q);
        const int4 te4 = *(const int4*)(tgt_order + e0 + 4 * q);
        const int se[4] = {se4.x, se4.y, se4.z, se4.w};
        const int te[4] = {te4.x, te4.y, te4.z, te4.w};
        s8v gs[4], gt[4];
#pragma unroll
        for (int r = 0; r < 4; ++r) {
            gs[r] = *(const s8v*)(sproj + ((size_t)b * NS + se[r]) * DD + np * 8);
            gt[r] = *(const s8v*)(tproj + ((size_t)b * NT + te[r]) * DD + np * 8);
        }

        f4v acc[8];
        const f4v zero = {0.f, 0.f, 0.f, 0.f};
#pragma unroll
        for (int t = 0; t < 8; ++t) acc[t] = zero;
#pragma unroll
        for (int c = 0; c < 4; ++c)
#pragma unroll
            for (int t = 0; t < 8; ++t)
                acc[t] = __builtin_amdgcn_mfma_f32_16x16x32_bf16(a[c], wfE[(c * 8 + t) * 64 + lane], acc[t], 0, 0, 0);

        // gathered add + silu, stats (x stored back into acc)
        float s1[4] = {0.f, 0.f, 0.f, 0.f};
        float s2[4] = {0.f, 0.f, 0.f, 0.f};
#pragma unroll
        for (int r = 0; r < 4; ++r) {
#pragma unroll
            for (int t = 0; t < 8; ++t) {
                float d = acc[t][r] + bf2f((unsigned short)gs[r][t]) + bf2f((unsigned short)gt[r][t]);
                float s = 1.0f / (1.0f + __expf(-d));
                float xv = d * s;
                acc[t][r] = xv;
                s1[r] += xv;
                s2[r] += xv * xv;
            }
        }
        // reduce across the 16 lanes of each quad (they span all 128 cols)
#pragma unroll
        for (int off = 1; off < 16; off <<= 1) {
#pragma unroll
            for (int r = 0; r < 4; ++r) {
                s1[r] += __shfl_xor(s1[r], off, 16);
                s2[r] += __shfl_xor(s2[r], off, 16);
            }
        }
        float mean[4], rstd[4];
#pragma unroll
        for (int r = 0; r < 4; ++r) {
            mean[r] = s1[r] * (1.0f / 128.0f);
            float var = s2[r] * (1.0f / 128.0f) - mean[r] * mean[r];
            rstd[r] = rsqrtf(var + 1e-5f);
        }
        // write out0 (= bond + y, fp32, streaming) and optional d_bond (bf16)
        const size_t crow = rowbase + (size_t)(4 * q) * DD;
#pragma unroll
        for (int r = 0; r < 4; ++r) {
            const size_t ro = crow + (size_t)r * DD;
#pragma unroll
            for (int t = 0; t < 8; ++t) {
                float y = (acc[t][r] - mean[r]) * rstd[r] * gv[t] + bv[t];
                const int col = 16 * t + np;
                __builtin_nontemporal_store(bond[ro + col] + y, &out0[ro + col]);
                if (dbond) __builtin_nontemporal_store(f2bf(y), &dbond[ro + col]);
            }
        }
    }
}

// ---------------------------------------------------------------------------
// K3: bond_reduce = (1/16) sum_k coef * d_bond[edge_order]; d_tgt = br@W_e2t +
//     tgt@W_t2t; out2 = tgt + LN(silu(d_tgt)).  d_bond from ws, or out0-bond.
// ---------------------------------------------------------------------------
__global__ __launch_bounds__(256, 4)
void tgt_kernel(const unsigned short* __restrict__ dbond,   // bf16 ws, or null
                const float* __restrict__ out0,             // fallback minuend
                const float* __restrict__ bond,             // fallback subtrahend
                const float* __restrict__ tgt,
                const s8v* __restrict__ wfE2T,
                const s8v* __restrict__ wfT2T,
                const float* __restrict__ coef,
                const int* __restrict__ edge_order,
                const float* __restrict__ g2,
                const float* __restrict__ b2,
                float* __restrict__ out2)
{
    const int lane = threadIdx.x & 63;
    const int wave = threadIdx.x >> 6;
    const int np = lane & 15, q = lane >> 4;
    const int b = blockIdx.y;

    const int tile = blockIdx.x * 4 + wave;
    if (tile >= NT / 16) return;
    const int t0 = tile * 16;
    const int myrow = t0 + np;                 // A-layout row (m = lane&15)

    // gather-accumulate in A-fragment element layout: cols 32c+8q+j
    float ad[4][8];
#pragma unroll
    for (int c = 0; c < 4; ++c)
#pragma unroll
        for (int j = 0; j < 8; ++j) ad[c][j] = 0.f;

    for (int kc = 0; kc < 4; ++kc) {
        const int4   e4 = *(const int4*)(edge_order + myrow * KK + 4 * kc);
        const float4 c4 = *(const float4*)(coef + myrow * KK + 4 * kc);
        const int   eo[4] = {e4.x, e4.y, e4.z, e4.w};
        const float cfv[4] = {c4.x, c4.y, c4.z, c4.w};
        if (dbond) {
#pragma unroll
            for (int k = 0; k < 4; ++k) {
                const s8v* p = (const s8v*)(dbond + ((size_t)b * EE + eo[k]) * DD);
                const float cf = cfv[k];
#pragma unroll
                for (int c = 0; c < 4; ++c) {
                    const s8v v = p[4 * c + q];
#pragma unroll
                    for (int j = 0; j < 8; ++j)
                        ad[c][j] += cf * bf2f((unsigned short)v[j]);
                }
            }
        } else {
#pragma unroll
            for (int k = 0; k < 4; ++k) {
                const float* p0 = out0 + ((size_t)b * EE + eo[k]) * DD + 8 * q;
                const float* p1 = bond + ((size_t)b * EE + eo[k]) * DD + 8 * q;
                const float cf = cfv[k];
#pragma unroll
                for (int c = 0; c < 4; ++c)
#pragma unroll
                    for (int j = 0; j < 8; ++j)
                        ad[c][j] += cf * (p0[32 * c + j] - p1[32 * c + j]);
            }
        }
    }
    // to bf16 A-frags (apply 1/K)
    s8v adf[4];
#pragma unroll
    for (int c = 0; c < 4; ++c)
#pragma unroll
        for (int j = 0; j < 8; ++j) adf[c][j] = (short)f2bf(ad[c][j] * (1.0f / 16.0f));

    const float* tb = tgt + ((size_t)b * NT + myrow) * DD + 8 * q;
    s8v at[4];
#pragma unroll
    for (int c = 0; c < 4; ++c) at[c] = load_afrag_f32(tb + 32 * c);

    f4v acc[8];
    const f4v zero = {0.f, 0.f, 0.f, 0.f};
#pragma unroll
    for (int t = 0; t < 8; ++t) acc[t] = zero;
#pragma unroll
    for (int c = 0; c < 4; ++c) {
#pragma unroll
        for (int t = 0; t < 8; ++t) {
            acc[t] = __builtin_amdgcn_mfma_f32_16x16x32_bf16(adf[c], wfE2T[(c * 8 + t) * 64 + lane], acc[t], 0, 0, 0);
            acc[t] = __builtin_amdgcn_mfma_f32_16x16x32_bf16(at[c],  wfT2T[(c * 8 + t) * 64 + lane], acc[t], 0, 0, 0);
        }
    }

    // epilogue: silu + LN + tgt add
    float gv[8], bv[8];
#pragma unroll
    for (int t = 0; t < 8; ++t) { gv[t] = g2[16 * t + np]; bv[t] = b2[16 * t + np]; }

    float s1[4] = {0.f, 0.f, 0.f, 0.f};
    float s2[4] = {0.f, 0.f, 0.f, 0.f};
#pragma unroll
    for (int r = 0; r < 4; ++r)
#pragma unroll
        for (int t = 0; t < 8; ++t) {
            float d = acc[t][r];
            float s = 1.0f / (1.0f + __expf(-d));
            float xv = d * s;
            acc[t][r] = xv;
            s1[r] += xv;
            s2[r] += xv * xv;
        }
#pragma unroll
    for (int off = 1; off < 16; off <<= 1) {
#pragma unroll
        for (int r = 0; r < 4; ++r) {
            s1[r] += __shfl_xor(s1[r], off, 16);
            s2[r] += __shfl_xor(s2[r], off, 16);
        }
    }
    float mean[4], rstd[4];
#pragma unroll
    for (int r = 0; r < 4; ++r) {
        mean[r] = s1[r] * (1.0f / 128.0f);
        float var = s2[r] * (1.0f / 128.0f) - mean[r] * mean[r];
        rstd[r] = rsqrtf(var + 1e-5f);
    }
    const size_t crow = ((size_t)b * NT + t0 + 4 * q) * DD;
#pragma unroll
    for (int r = 0; r < 4; ++r) {
        const size_t ro = crow + (size_t)r * DD;
#pragma unroll
        for (int t = 0; t < 8; ++t) {
            float y = (acc[t][r] - mean[r]) * rstd[r] * gv[t] + bv[t];
            const int col = 16 * t + np;
            __builtin_nontemporal_store(tgt[ro + col] + y, &out2[ro + col]);
        }
    }
}

// K4: out1 = src (plain fp32 copy)
__global__ void copy_kernel(const u4v* __restrict__ s, u4v* __restrict__ d, int n) {
    int i = blockIdx.x * blockDim.x + threadIdx.x;
    const int st = gridDim.x * blockDim.x;
    for (; i < n; i += st) {
        u4v v = __builtin_nontemporal_load(&s[i]);
        __builtin_nontemporal_store(v, &d[i]);
    }
}

extern "C" void kernel_launch(void* const* d_in, const int* in_sizes, int n_in,
                              void* d_out, int out_size, void* d_ws, size_t ws_size,
                              hipStream_t stream)
{
    const float* bond = (const float*)d_in[0];
    const float* src  = (const float*)d_in[1];
    const float* tgt  = (const float*)d_in[2];
    const float* Ws2e = (const float*)d_in[3];
    const float* Wt2e = (const float*)d_in[4];
    const float* We2e = (const float*)d_in[5];
    const float* g1   = (const float*)d_in[6];
    const float* b1   = (const float*)d_in[7];
    const float* We2t = (const float*)d_in[8];
    const float* Wt2t = (const float*)d_in[9];
    const float* g2   = (const float*)d_in[10];
    const float* b2   = (const float*)d_in[11];
    const float* coef = (const float*)d_in[12];
    const int* src_order  = (const int*)d_in[13];
    const int* tgt_order  = (const int*)d_in[14];
    const int* edge_order = (const int*)d_in[15];

    float* out0 = (float*)d_out;
    float* out1 = out0 + (size_t)BB * EE * DD;   // src slot; staging: s_proj bf16 + wfrags
    float* out2 = out1 + (size_t)BB * NS * DD;   // tgt slot; staging: t_proj bf16

    unsigned short* sproj = (unsigned short*)out1;   // 10.24 MB bf16 in 20.48 MB slot
    unsigned short* tproj = (unsigned short*)out2;

    // bf16 fragment-major weights in the unused tail of the out1 slot
    // (sproj occupies the first BB*NS*DD u16 = 10.24 MB; tail has 10.24 MB free;
    //  copy_kernel overwrites out1 only after tgt_kernel has consumed the weights)
    unsigned short* wfrag = (unsigned short*)out1 + (size_t)BB * NS * DD;

    const size_t dbond_bytes = (size_t)BB * EE * DD * 2;   // 163.84 MB
    unsigned short* dbond = (ws_size >= dbond_bytes) ? (unsigned short*)d_ws : nullptr;

    // K0: weight fragment prep (order: Ws2e, Wt2e, We2e, We2t, Wt2t)
    wprep_kernel<<<dim3(5), 256, 0, stream>>>(Ws2e, Wt2e, We2e, We2t, Wt2t, wfrag);
    const s8v* wfS   = (const s8v*)(wfrag + 0 * (size_t)WFRAG_U16);
    const s8v* wfT   = (const s8v*)(wfrag + 1 * (size_t)WFRAG_U16);
    const s8v* wfE   = (const s8v*)(wfrag + 2 * (size_t)WFRAG_U16);
    const s8v* wfE2T = (const s8v*)(wfrag + 3 * (size_t)WFRAG_U16);
    const s8v* wfT2T = (const s8v*)(wfrag + 4 * (size_t)WFRAG_U16);

    // K1: projections into bf16 permuted staging (inside out1/out2 slots)
    proj_kernel<<<dim3(157, 2), 256, 0, stream>>>(src, tgt, wfS, wfT, sproj, tproj);

    // K2: bond update, writes out0 (fp32) and optionally ws d_bond (bf16)
    bond_kernel<<<dim3(256, BB), 256, 0, stream>>>(bond, wfE, sproj, tproj,
                                                   src_order, tgt_order, g1, b1,
                                                   out0, dbond);

    // K3: target update (overwrites out2 after K2 consumed t_proj)
    tgt_kernel<<<dim3(157, BB), 256, 0, stream>>>(dbond, out0, bond, tgt, wfE2T, wfT2T,
                                                  coef, edge_order, g2, b2, out2);

    // K4: out1 = src copy (after K3 consumed the wfrag staging in out1's tail)
    copy_kernel<<<dim3(1024), 256, 0, stream>>>((const u4v*)src, (u4v*)out1,
                                                (int)((size_t)BB * NS * DD / 4));
}